// Round 12
// baseline (31.012 us; speedup 1.0000x reference)
//
#include <hip/hip_runtime.h>
#include <cmath>

typedef __attribute__((ext_vector_type(8))) short short8;
typedef __attribute__((ext_vector_type(4))) float f32x4;

#define NB 32
#define MU_OUT_SZ (NB*100*64)   // 204800
#define LDAP 56                 // shorts per (h,w) cell in LDS (112 B padded)

__device__ inline unsigned short f2bf(float f) {
  unsigned u = __builtin_bit_cast(unsigned, f);
  u += 0x7fffu + ((u >> 16) & 1u);
  return (unsigned short)(u >> 16);
}

// ---------------- prepW: coalesced stage of w slice -> LDS -> fragment pack (proven) ----------------
__global__ __launch_bounds__(256) void prepW(
    const float* __restrict__ w_mu, const float* __restrict__ w_sigma,
    unsigned short* __restrict__ wf) {
  __shared__ float wsh[2048];              // this ij's 32 K-rows x 64 cols (8 KB)
  const int ij = blockIdx.x, t = threadIdx.x;
  const float4* src = (const float4*)(w_mu + (size_t)ij * 2048);
  ((float4*)wsh)[t]       = src[t];
  ((float4*)wsh)[t + 256] = src[t + 256];
  __syncthreads();
#pragma unroll
  for (int id0 = 0; id0 < 512; id0 += 256) {
    const int id = id0 + t;
    const int kind = id >> 8;              // 0: W, 1: W^2 + sp
    const int rest = id & 255;
    const int n = rest >> 6, l = rest & 63;
    const int col = n * 16 + (l & 15);     // output channel k
    const int m0 = (l >> 4) * 8;           // K-row base within this ij
    const float sp = log1pf(expf(w_sigma[col]));
    unsigned short v[8];
#pragma unroll
    for (int i = 0; i < 8; ++i) {
      const float wv = wsh[(m0 + i) * 64 + col];
      const float x = kind ? (wv * wv + sp) : wv;
      v[i] = f2bf(x);
    }
    uint4 pk;
    pk.x = v[0] | ((unsigned)v[1] << 16);
    pk.y = v[2] | ((unsigned)v[3] << 16);
    pk.z = v[4] | ((unsigned)v[5] << 16);
    pk.w = v[6] | ((unsigned)v[7] << 16);
    *(uint4*)(wf + (size_t)((ij * 8 + kind * 4 + n) * 64 + l) * 8) = pk;
  }
}

// ---------------- fusedB: balanced 256-block fused gemm + stream ----------------
// block (s,b): owns p rows [s0, s0+nr): nr=13 for s<4, else 12. One block per CU.
__global__ __launch_bounds__(512) void fusedB(
    const float* __restrict__ mu_in, const float* __restrict__ Sigma_in,
    const unsigned short* __restrict__ wf, const float* __restrict__ w_sigma,
    float* __restrict__ out) {
  __shared__ unsigned short mu_sh[196 * LDAP];   // 21952 B
  __shared__ unsigned short sd_sh[98 * LDAP];    // 7 h-rows x 14, 10976 B
  __shared__ float g_sh[16][100];                // 6400 B
  __shared__ float dv_sh[16][64];                // 4096 B
  const int s = blockIdx.x;            // 0..7
  const int b = blockIdx.y;
  const int t = threadIdx.x, l = t & 63, w = t >> 6;
  const int nr = (s < 4) ? 13 : 12;
  const int s0 = (s < 4) ? 13 * s : 52 + 12 * (s - 4);
  const int hlo = s0 / 10;

  // ---- stage mu[b] (all 196 cells) ----
  const float4* mu4 = (const float4*)(mu_in + (size_t)b * 6272);
  for (int f = t; f < 1568; f += 512) {
    const float4 v = mu4[f];
    const int row = f >> 3, c = (f & 7) * 4;
    ushort4 pv;
    pv.x = f2bf(v.x); pv.y = f2bf(v.y); pv.z = f2bf(v.z); pv.w = f2bf(v.w);
    *(ushort4*)(mu_sh + row * LDAP + c) = pv;
  }
  // ---- stage Sigma-diag for 7 h-rows starting hlo (clamped to h<=13) ----
  for (int f = t; f < 784; f += 512) {
    const int cell = f >> 3, c = (f & 7) * 4;
    const int hl = cell / 14, ww = cell - hl * 14;
    int h = hlo + hl; if (h > 13) h = 13;
    const int n = h * 14 + ww;
    const float4 sv = *(const float4*)(Sigma_in +
        ((size_t)(b * 196 + n) * 196 + n) * 32 + c);
    ushort4 ps;
    ps.x = f2bf(sv.x); ps.y = f2bf(sv.y); ps.z = f2bf(sv.z); ps.w = f2bf(sv.w);
    *(ushort4*)(sd_sh + cell * LDAP + c) = ps;
  }
  __syncthreads();

  // ---- MFMA phase (R9 wave plan: w0-6 G-tiles, w0-3 mu, w4-7 dv) ----
  const int laneP = l & 15, g16 = (l >> 4) * 8;
  const int pA = (s0 + laneP > 99) ? 99 : s0 + laneP;
  const int baseA = ((pA / 10) * 14 + (pA % 10)) * LDAP + g16;
  const int baseS = ((pA / 10 - hlo) * 14 + (pA % 10)) * LDAP + g16;
  const bool doG = (w < 7);
  const int q = w * 16 + laneP;
  const int qc = q > 99 ? 99 : q;
  const int baseB = ((qc / 10) * 14 + (qc % 10)) * LDAP + g16;
  const bool doMu = (w < 4);
  const int n = doMu ? w : (w - 4);                // k-tile
  const int kslot = doMu ? n : (4 + n);

  const short8* wfp = (const short8*)wf;
  short8 fw = wfp[(size_t)kslot * 64 + l];         // prefetch ij=0
  f32x4 aG = {}, aX = {};
  for (int ij = 0; ij < 25; ++ij) {
    const short8 fw_n = (ij < 24) ? wfp[(size_t)((ij + 1) * 8 + kslot) * 64 + l] : fw;
    const int off = ((ij / 5) * 14 + (ij % 5)) * LDAP;
    if (doG) {
      const short8 fA = *(const short8*)(mu_sh + baseA + off);
      const short8 fB = *(const short8*)(mu_sh + baseB + off);
      aG = __builtin_amdgcn_mfma_f32_16x16x32_bf16(fA, fB, aG, 0, 0, 0);
      if (doMu) {
        aX = __builtin_amdgcn_mfma_f32_16x16x32_bf16(fA, fw, aX, 0, 0, 0);
      } else {
        const short8 fS = *(const short8*)(sd_sh + baseS + off);
        aX = __builtin_amdgcn_mfma_f32_16x16x32_bf16(fS, fw, aX, 0, 0, 0);
      }
    } else {
      const short8 fS = *(const short8*)(sd_sh + baseS + off);
      aX = __builtin_amdgcn_mfma_f32_16x16x32_bf16(fS, fw, aX, 0, 0, 0);
    }
    fw = fw_n;
  }

  const int prow0 = (l >> 4) * 4;
  if (doG && q < 100) {
#pragma unroll
    for (int j = 0; j < 4; ++j) g_sh[prow0 + j][q] = aG[j];
  }
  const int k = n * 16 + laneP;
  if (doMu) {
    float* mo = out + (size_t)b * 6400;
#pragma unroll
    for (int j = 0; j < 4; ++j) {
      const int lr = prow0 + j;
      if (lr < nr) mo[(s0 + lr) * 64 + k] = aX[j];
    }
  } else {
#pragma unroll
    for (int j = 0; j < 4; ++j) dv_sh[prow0 + j][k] = aX[j];
  }
  __syncthreads();

  // ---- write phase: nr x 100 x 64 floats, balanced across all 256 blocks ----
  const int k4 = (t & 15) * 4;         // constant per thread (512 % 16 == 0)
  const float4 wsv = *(const float4*)(w_sigma + k4);
  f32x4 sp4;
  sp4.x = log1pf(expf(wsv.x));
  sp4.y = log1pf(expf(wsv.y));
  sp4.z = log1pf(expf(wsv.z));
  sp4.w = log1pf(expf(wsv.w));
  float* sig = out + MU_OUT_SZ + (size_t)(b * 100 + s0) * 6400;
  const int total = nr * 1600;         // nr * 100q * 16 float4
  for (int l4 = t; l4 < total; l4 += 512) {
    const int rowq = l4 >> 4;          // row*100 + q, < 1300
    const int row = rowq / 100;
    const int qq = rowq - row * 100;
    const float g = g_sh[row][qq];
    f32x4 v;
    v.x = sp4.x * g; v.y = sp4.y * g; v.z = sp4.z * g; v.w = sp4.w * g;
    if (qq == s0 + row) {
      const float4 dvv = *(const float4*)&dv_sh[row][k4];
      v.x += dvv.x; v.y += dvv.y; v.z += dvv.z; v.w += dvv.w;
    }
    v.x = (qq == k4)     ? fabsf(v.x) : v.x;
    v.y = (qq == k4 + 1) ? fabsf(v.y) : v.y;
    v.z = (qq == k4 + 2) ? fabsf(v.z) : v.z;
    v.w = (qq == k4 + 3) ? fabsf(v.w) : v.w;
    *(f32x4*)(sig + (size_t)l4 * 4) = v;
  }
}

extern "C" void kernel_launch(void* const* d_in, const int* in_sizes, int n_in,
                              void* d_out, int out_size, void* d_ws, size_t ws_size,
                              hipStream_t stream) {
  const float* mu_in    = (const float*)d_in[0];
  const float* Sigma_in = (const float*)d_in[1];
  const float* w_mu     = (const float*)d_in[2];
  const float* w_sigma  = (const float*)d_in[3];
  float* out = (float*)d_out;
  unsigned short* wf = (unsigned short*)d_ws;   // 204800 B

  prepW<<<25, 256, 0, stream>>>(w_mu, w_sigma, wf);
  fusedB<<<dim3(8, NB), 512, 0, stream>>>(mu_in, Sigma_in, wf, w_sigma, out);
}